// Round 1
// 181.152 us; speedup vs baseline: 1.0315x; 1.0315x over previous
//
#include <hip/hip_runtime.h>
#include <math.h>

// x:     [4, 3, 1024, 1024] f32
// param: [4, 72, 256, 256]  f32 ; channel ch = c*24 + i*8 + z = (3c+i)*8 + z
// out:   [4, 3, 1024, 1024] f32 = tanh(sum_i trilinear(curve))
//
// 128x16 pixel tile per 1024-thread block, 2 px/thread (vertical pair, 8 apart).
// Footprint: 6 rows x 34 cells x 72 ch staged to LDS = 7.2 staged dw/px
// (vs 13.9 for the old 256x4 tile).
//  - LDS cell stride 73 dw (%32 = 9, odd) -> staging writes 2 lanes/bank (free)
//  - XCD-contiguous block swizzle: each XCD walks a contiguous ht range; its
//    sliding param window (~2.7 MB) fits the per-XCD 4 MB L2
//  - x loads / out stores nontemporal: don't evict param from L2
#define IMG 1024
#define HW (IMG * IMG)
#define TS 256
#define CH_STRIDE (TS * TS)
#define PARAM_B_STRIDE (72 * CH_STRIDE)
#define S_CONST (255.0f / 1023.0f)

#define ROWS 6
#define CELLS 34
#define CELL_DW 73                    // 72 + 1 pad; %32 = 9 (odd)
#define ROW_DW (CELLS * CELL_DW)      // 2482
#define LDS_DW (ROWS * ROW_DW)        // 14892 dw = 59568 B (2 blocks/CU)
#define RUNS (ROWS * 72)              // 432
#define STAGE_DW (RUNS * CELLS)       // 14688

__global__ __launch_bounds__(1024, 8) void curve3d_fused(
    const float* __restrict__ x, const float* __restrict__ param,
    float* __restrict__ out)
{
    __shared__ float sh[LDS_DW];
    // 2048 blocks, 2048 % 8 == 0 -> simple bijective XCD swizzle.
    // XCD n gets rblk [n*256, (n+1)*256): one batch, contiguous ht, all wt.
    int blk = blockIdx.x;
    blk = (blk & 7) * 256 + (blk >> 3);
    int wt = blk & 7;                 // 8 w-tiles of 128
    int ht = (blk >> 3) & 63;         // 64 h-tiles of 16
    int b  = blk >> 9;                // 4 batches
    int tid = threadIdx.x;

    int w0 = wt * 128, h0 = ht * 16;
    int xb = (int)((float)w0 * S_CONST);  // cells xb..xb+33 cover the tile
    int yb = (int)((float)h0 * S_CONST);  // rows  yb..yb+5

    // ---- pixel mapping + x loads early (independent of LDS) ----
    int tw = tid & 127, th = tid >> 7;    // th 0..7; pixels (th, th+8)
    int w = w0 + tw;
    int ha = h0 + th;
    const float* xp = x + (size_t)b * 3 * HW + (size_t)ha * IMG + w;
    float xv[2][3];
#pragma unroll
    for (int i = 0; i < 3; ++i) {
        xv[0][i] = __builtin_nontemporal_load(xp + (size_t)i * HW);
        xv[1][i] = __builtin_nontemporal_load(xp + (size_t)i * HW + 8 * IMG);
    }

    // ---- staging: 432 runs (row,ch) x 34 dw, linear index over 14688 dw ----
    const float* pb = param + (size_t)b * PARAM_B_STRIDE;
#pragma unroll
    for (int j = 0; j < 15; ++j) {
        int idx = tid + j * 1024;
        if (j < 14 || idx < STAGE_DW) {
            int run = idx / CELLS;        // magic-div by 34
            int off = idx - run * CELLS;
            int row = run / 72;           // magic-div by 72
            int ch  = run - row * 72;
            int ys = min(yb + row, 255);
            int xs = min(xb + off, 255);
            sh[row * ROW_DW + off * CELL_DW + ch] =
                pb[(size_t)ch * CH_STRIDE + ys * TS + xs];
        }
    }

    // ---- z prep for both pixels (no LDS dependence, before barrier) ----
    int zi[2][3]; float wz[2][3];
#pragma unroll
    for (int p = 0; p < 2; ++p)
#pragma unroll
        for (int i = 0; i < 3; ++i) {
            float f = fminf(fmaxf(fmaf(xv[p][i], 3.5f, 3.5f), 0.0f), 7.0f);
            int z = min((int)f, 6);
            zi[p][i] = z;
            wz[p][i] = f - (float)z;
        }

    __syncthreads();

    // ---- shared x-geometry (same w for both pixels) ----
    float ixf = (float)w * S_CONST; int x0 = (int)ixf; float wx = ixf - (float)x0;
    int cb0 = (x0 - xb) * CELL_DW;
    int cb1 = (min(x0 + 1, 255) - xb) * CELL_DW;
    float u0 = 1.0f - wx;

    float* op = out + (size_t)b * 3 * HW + (size_t)ha * IMG + w;

#pragma unroll
    for (int p = 0; p < 2; ++p) {
        int h = ha + p * 8;
        float iyf = (float)h * S_CONST; int y0 = (int)iyf; float wy = iyf - (float)y0;
        int rb0 = (y0 - yb) * ROW_DW;
        int rb1 = (min(y0 + 1, 255) - yb) * ROW_DW;
        float v0 = 1.0f - wy;
        float wcs[4] = {v0 * u0, v0 * wx, wy * u0, wy * wx};
        int bofs[4] = {rb0 + cb0, rb0 + cb1, rb1 + cb0, rb1 + cb1};
        float* opp = op + (size_t)(p * 8) * IMG;
#pragma unroll
        for (int c = 0; c < 3; ++c) {
            float acc = 0.0f;
#pragma unroll
            for (int i = 0; i < 3; ++i) {
                int off = (c * 3 + i) * 8 + zi[p][i];
                float wzi = wz[p][i];
#pragma unroll
                for (int k = 0; k < 4; ++k) {
                    float2 v;
                    __builtin_memcpy(&v, &sh[bofs[k] + off], 8);  // ds_read2_b32
                    float wb = wcs[k] * wzi;
                    float wa = wcs[k] - wb;
                    acc = fmaf(v.x, wa, fmaf(v.y, wb, acc));
                }
            }
            float e = __expf(2.0f * acc);
            __builtin_nontemporal_store(1.0f - 2.0f / (e + 1.0f),
                                        opp + (size_t)c * HW);
        }
    }
}

extern "C" void kernel_launch(void* const* d_in, const int* in_sizes, int n_in,
                              void* d_out, int out_size, void* d_ws, size_t ws_size,
                              hipStream_t stream) {
    const float* x = (const float*)d_in[0];
    const float* param = (const float*)d_in[1];
    float* out = (float*)d_out;
    // blocks: 4 batches * 64 h-tiles * 8 w-tiles
    curve3d_fused<<<dim3(4 * 64 * 8), dim3(1024), 0, stream>>>(x, param, out);
}

// Round 2
// 177.945 us; speedup vs baseline: 1.0501x; 1.0180x over previous
//
#include <hip/hip_runtime.h>
#include <math.h>

// x:     [4, 3, 1024, 1024] f32
// param: [4, 72, 256, 256]  f32 ; channel ch = c*24 + i*8 + z = (3c+i)*8 + z
// out:   [4, 3, 1024, 1024] f32 = tanh(sum_i trilinear(curve))
//
// 128x16 pixel tile per 1024-thread block, 2 px/thread (vertical pair, 8 apart).
// Wave = 16x4 pixel patch (lane bits [3:0]=x, [5:4]=y): a wave spans only
// 4-5 cells x <=2 rows, so LDS reads are mostly same-address broadcasts ->
// bank conflicts structurally eliminated (vs 9.6M conflict cycles with the
// 64x1 wave mapping, where 16 cells x data-dependent z always collide).
//  - LDS cell stride 73 dw (%32=9 odd): staging writes 2 lanes/bank (free)
//  - ROW_DW%32=18: only (dRow=+-1, dCell=-+2, dz=0) collides -> rare, 2-way
//  - XCD-contiguous block swizzle: per-XCD sliding param window ~2.7MB in L2
//  - x loads nontemporal (streaming, don't evict param); stores NORMAL
//    (nt stores inflated WRITE_SIZE 49->64 MB in round 1)
//  - inner loop: t = fma(wz, vy-vx, vx); acc = fma(wk, t, acc) (3 VALU/read),
//    LDS base per (i,k), (c*3+i)*8 folds into ds_read2 imm offset
#define IMG 1024
#define HW (IMG * IMG)
#define TS 256
#define CH_STRIDE (TS * TS)
#define PARAM_B_STRIDE (72 * CH_STRIDE)
#define S_CONST (255.0f / 1023.0f)

#define ROWS 6
#define CELLS 34
#define CELL_DW 73                    // 72 + 1 pad; %32 = 9 (odd)
#define ROW_DW (CELLS * CELL_DW)      // 2482 ; %32 = 18
#define LDS_DW (ROWS * ROW_DW)        // 14892 dw = 59568 B (2 blocks/CU)
#define RUNS (ROWS * 72)              // 432

__global__ __launch_bounds__(1024, 8) void curve3d_fused(
    const float* __restrict__ x, const float* __restrict__ param,
    float* __restrict__ out)
{
    __shared__ float sh[LDS_DW];
    // 2048 blocks, 2048 % 8 == 0 -> bijective XCD swizzle; XCD n gets a
    // contiguous range of (b, ht) so its param window slides through L2.
    int blk = blockIdx.x;
    blk = (blk & 7) * 256 + (blk >> 3);
    int wt = blk & 7;                 // 8 w-tiles of 128
    int ht = (blk >> 3) & 63;         // 64 h-tiles of 16
    int b  = blk >> 9;                // 4 batches
    int tid = threadIdx.x;

    int w0 = wt * 128, h0 = ht * 16;
    int xb = (int)((float)w0 * S_CONST);  // cells xb..xb+33 cover the tile
    int yb = (int)((float)h0 * S_CONST);  // rows  yb..yb+5

    // ---- pixel mapping: wave = 16x4 patch ----
    int wx = tid & 15;
    int wyl = (tid >> 4) & 3;
    int pxp = (tid >> 6) & 7;         // patch col (8 x 16 = 128 wide)
    int pyp = tid >> 9;               // patch row (2 x 4 = 8 tall, +8 for p=1)
    int tw = pxp * 16 + wx;
    int th = pyp * 4 + wyl;
    int w = w0 + tw;
    int ha = h0 + th;                 // pixels (ha, ha+8)

    const float* xp = x + (size_t)b * 3 * HW + (size_t)ha * IMG + w;
    float xv[2][3];
#pragma unroll
    for (int i = 0; i < 3; ++i) {
        xv[0][i] = __builtin_nontemporal_load(xp + (size_t)i * HW);
        xv[1][i] = __builtin_nontemporal_load(xp + (size_t)i * HW + 8 * IMG);
    }

    // ---- staging: 432 runs (row,ch) x 34 cells; div-free index math ----
    // main: cells 0..31, one 32-lane group per run (xb+31 <= 254: no clamp)
    const float* pb = param + (size_t)b * PARAM_B_STRIDE;
    {
        int off = tid & 31;
        int g = tid >> 5;             // 0..31
#pragma unroll
        for (int j = 0; j < 14; ++j) {
            int run = g + j * 32;     // 0..447; 432 used
            if (run < RUNS) {
                unsigned row = (unsigned)run / 72u;
                int ch = run - (int)row * 72;
                int ys = min(yb + (int)row, 255);
                sh[(int)row * ROW_DW + off * CELL_DW + ch] =
                    pb[(size_t)ch * CH_STRIDE + ys * TS + (xb + off)];
            }
        }
    }
    // tail: cells 32,33 (864 loads; border clamp applies here)
    if (tid < 2 * RUNS) {
        int run = tid >> 1;
        int xx = 32 + (tid & 1);
        unsigned row = (unsigned)run / 72u;
        int ch = run - (int)row * 72;
        int ys = min(yb + (int)row, 255);
        int xs = min(xb + xx, 255);
        sh[(int)row * ROW_DW + xx * CELL_DW + ch] =
            pb[(size_t)ch * CH_STRIDE + ys * TS + xs];
    }

    // ---- z prep for both pixels (no LDS dependence, before barrier) ----
    int zi[2][3]; float wz[2][3];
#pragma unroll
    for (int p = 0; p < 2; ++p)
#pragma unroll
        for (int i = 0; i < 3; ++i) {
            float f = fminf(fmaxf(fmaf(xv[p][i], 3.5f, 3.5f), 0.0f), 7.0f);
            int z = min((int)f, 6);
            zi[p][i] = z;
            wz[p][i] = f - (float)z;
        }

    __syncthreads();

    // ---- shared x-geometry (same w for both pixels) ----
    float ixf = (float)w * S_CONST; int x0 = (int)ixf; float wxf = ixf - (float)x0;
    int cb0 = (x0 - xb) * CELL_DW;
    int cb1 = (min(x0 + 1, 255) - xb) * CELL_DW;
    float u0 = 1.0f - wxf;

    float* op = out + (size_t)b * 3 * HW + (size_t)ha * IMG + w;

#pragma unroll
    for (int p = 0; p < 2; ++p) {
        int h = ha + p * 8;
        float iyf = (float)h * S_CONST; int y0 = (int)iyf; float wyf = iyf - (float)y0;
        int rb0 = (y0 - yb) * ROW_DW;
        int rb1 = (min(y0 + 1, 255) - yb) * ROW_DW;
        float v0 = 1.0f - wyf;
        float wcs[4] = {v0 * u0, v0 * wxf, wyf * u0, wyf * wxf};
        int bofs[4] = {rb0 + cb0, rb0 + cb1, rb1 + cb0, rb1 + cb1};

        float acc[3] = {0.0f, 0.0f, 0.0f};
#pragma unroll
        for (int i = 0; i < 3; ++i) {
            float wzi = wz[p][i];
            const float* bi = sh + zi[p][i];
#pragma unroll
            for (int k = 0; k < 4; ++k) {
                const float* bp = bi + bofs[k];
                float wk = wcs[k];
#pragma unroll
                for (int c = 0; c < 3; ++c) {
                    float2 v;
                    __builtin_memcpy(&v, bp + (c * 3 + i) * 8, 8);  // ds_read2
                    float t = fmaf(wzi, v.y - v.x, v.x);
                    acc[c] = fmaf(wk, t, acc[c]);
                }
            }
        }
        float* opp = op + (size_t)(p * 8) * IMG;
#pragma unroll
        for (int c = 0; c < 3; ++c) {
            float e = __expf(2.0f * acc[c]);
            opp[(size_t)c * HW] = 1.0f - 2.0f / (e + 1.0f);
        }
    }
}

extern "C" void kernel_launch(void* const* d_in, const int* in_sizes, int n_in,
                              void* d_out, int out_size, void* d_ws, size_t ws_size,
                              hipStream_t stream) {
    const float* x = (const float*)d_in[0];
    const float* param = (const float*)d_in[1];
    float* out = (float*)d_out;
    // blocks: 4 batches * 64 h-tiles * 8 w-tiles
    curve3d_fused<<<dim3(4 * 64 * 8), dim3(1024), 0, stream>>>(x, param, out);
}